// Round 17
// baseline (690.893 us; speedup 1.0000x reference)
//
#include <hip/hip_runtime.h>

#define KC   21
#define BB   8
#define CC   256
#define HWP  65536
#define SRC  4096
#define NS   128
#define PC   32

// d_ws layout: L = 524288 BYTES | partialw f32 @ byte 524288 | partial f32 | probe scratch @ >=128MB
#define WSF_PARTW 131072
#define WSF_PART  (WSF_PARTW + BB*NS*KC)

// ---- k1: per-pixel argmax + gt-match -> label map (EXACT R16) ---------------
__global__ __launch_bounds__(256, 2)
void k1_classify(const float* __restrict__ preds,
                 const int*   __restrict__ masks,
                 unsigned char* __restrict__ L,
                 float* __restrict__ out)
{
    int tid = threadIdx.x;
    if (blockIdx.x == 0) {
        float4* o4 = reinterpret_cast<float4*>(out);
#pragma unroll
        for (int i = 0; i < (KC * CC / 4 + 255) / 256; ++i) {
            int j = tid + i * 256;
            if (j < KC * CC / 4) o4[j] = make_float4(0.f, 0.f, 0.f, 0.f);
        }
    }
    int idx = blockIdx.x * 256 + tid;
    int b   = idx >> 14;
    int hw4 = (idx & 16383) << 2;

    const float* pb = preds + (size_t)b * KC * HWP + hw4;
    float va[4][KC];
#pragma unroll
    for (int k = 0; k < KC; ++k) {
        float4 t = *reinterpret_cast<const float4*>(pb + (size_t)k * HWP);
        va[0][k] = t.x; va[1][k] = t.y; va[2][k] = t.z; va[3][k] = t.w;
    }
    int4 mm = *reinterpret_cast<const int4*>(masks + b * HWP + hw4);
    int mk[4] = { mm.x, mm.y, mm.z, mm.w };

    uchar4 r;
    unsigned char* rp = reinterpret_cast<unsigned char*>(&r);
#pragma unroll
    for (int j = 0; j < 4; ++j) {
        float best = va[j][0];
        int   bi   = 0;
#pragma unroll
        for (int k = 1; k < KC; ++k)
            if (va[j][k] > best) { best = va[j][k]; bi = k; }
        rp[j] = (mk[j] == bi) ? (unsigned char)bi : (unsigned char)255;
    }
    *reinterpret_cast<uchar4*>(L + (size_t)b * HWP + hw4) = r;
}

// ---- shared device helper: the gather (exact R16 body) ----------------------
__device__ __forceinline__ void gather_ws(const unsigned char* __restrict__ L,
                                          float* ws, int b, int y, int x0c, int tid)
{
    int r = tid >> 6, cb = tid & 63;
    int h = 4 * y - 2 + r;
    if ((unsigned)h < 256u) {
        float sy = h * 0.25f - 0.375f;
        int   yt = (int)floorf(sy);
        float wy = sy - (float)yt;
        int ya = yt < 0 ? 0 : yt;
        int yb = yt + 1 > 63 ? 63 : yt + 1;
        float wyy = ((ya == y) ? (1.f - wy) : 0.f) + ((yb == y) ? wy : 0.f);
        if (wyy != 0.f) {
            const unsigned char* Lrow = L + ((size_t)b << 16) + ((size_t)h << 8);
            int wb0 = 4 * x0c - 2;
#pragma unroll
            for (int j = 0; j < 3; ++j) {
                int col = cb + j * 64;
                int w = wb0 + col;
                if (col < 136 && (unsigned)w < 256u) {
                    int k = Lrow[w];
                    if (k < KC) {
                        float sx = w * 0.25f - 0.375f;
                        int   xt = (int)floorf(sx);
                        float wx = sx - (float)xt;
                        int xa = xt < 0 ? 0 : xt;
                        int xb = xt + 1 > 63 ? 63 : xt + 1;
                        if (xa >= x0c && xa < x0c + PC)
                            atomicAdd(&ws[k * PC + xa - x0c], wyy * (1.f - wx));
                        if (xb >= x0c && xb < x0c + PC)
                            atomicAdd(&ws[k * PC + xb - x0c], wyy * wx);
                    }
                }
            }
        }
    }
}

// ---- k2: EXACT R16 version (passed, absmax 3e-5) -----------------------------
__global__ __launch_bounds__(512, 8)
void k2_contract(const float* __restrict__ feats,
                 const unsigned char* __restrict__ L,
                 float* __restrict__ partial,
                 float* __restrict__ partialw)
{
    __shared__ float ws[KC * PC];
    __shared__ float scr[KC * CC];
    int s = blockIdx.x, b = blockIdx.y;
    int tid = threadIdx.x;
    int y = s >> 1, x0c = (s & 1) * PC;
    int p0 = y * 64 + x0c;
    int cp = tid & 255, psub = tid >> 8, pw = psub * 16;

    if (tid < KC * PC / 4)
        *reinterpret_cast<float4*>(ws + tid * 4) = make_float4(0.f, 0.f, 0.f, 0.f);

    float f[16];
    {
        const float* frow = feats + (size_t)(b * CC + cp) * SRC + p0 + pw;
#pragma unroll
        for (int q = 0; q < 4; ++q) {
            float4 t = *reinterpret_cast<const float4*>(frow + q * 4);
            f[q * 4 + 0] = t.x; f[q * 4 + 1] = t.y;
            f[q * 4 + 2] = t.z; f[q * 4 + 3] = t.w;
        }
    }
    __syncthreads();
    gather_ws(L, ws, b, y, x0c, tid);
    __syncthreads();

    float swcnt = 0.f;
    if (tid < KC) {
#pragma unroll
        for (int p = 0; p < PC; ++p) swcnt += ws[tid * PC + ((p + tid) & (PC - 1))];
    }

    float acc[KC];
#pragma unroll
    for (int k = 0; k < KC; ++k) {
        const float* wk = ws + k * PC + pw;
        float a0 = 0.f, a1 = 0.f, a2 = 0.f, a3 = 0.f;
#pragma unroll
        for (int q = 0; q < 4; ++q) {
            float4 w4 = *reinterpret_cast<const float4*>(wk + q * 4);
            a0 += w4.x * f[q * 4 + 0];
            a1 += w4.y * f[q * 4 + 1];
            a2 += w4.z * f[q * 4 + 2];
            a3 += w4.w * f[q * 4 + 3];
        }
        acc[k] = (a0 + a1) + (a2 + a3);
    }

    if (psub == 1) {
#pragma unroll
        for (int k = 0; k < KC; ++k) scr[k * CC + cp] = acc[k];
    }
    __syncthreads();
    if (psub == 0) {
        float* op = partial + ((size_t)(b * NS + s)) * KC * CC + cp;
#pragma unroll
        for (int k = 0; k < KC; ++k)
            op[(size_t)k * CC] = acc[k] + scr[k * CC + cp];
    }
    if (tid < KC)
        partialw[(size_t)(b * NS + s) * KC + tid] = swcnt;
}

// ---- ABLATION PROBES (write to dead scratch; MODE 0=full 1=nostore 2=nogather 3=nofma)
template<int MODE>
__global__ __launch_bounds__(512, 8)
void k2_probe(const float* __restrict__ feats,
              const unsigned char* __restrict__ L,
              float* __restrict__ scratch)
{
    __shared__ float ws[KC * PC];
    __shared__ float scr[KC * CC];
    int s = blockIdx.x, b = blockIdx.y;
    int tid = threadIdx.x;
    int y = s >> 1, x0c = (s & 1) * PC;
    int p0 = y * 64 + x0c;
    int cp = tid & 255, psub = tid >> 8, pw = psub * 16;
    const int NREP = (MODE == 0) ? 2 : 3;

#pragma unroll 1
    for (int rep = 0; rep < NREP; ++rep) {
        if constexpr (MODE == 2) {
            for (int i = tid; i < KC * PC; i += 512)
                ws[i] = (float)((i * 37) & 31) * 0.03125f;   // deterministic fill
        } else {
            if (tid < KC * PC / 4)
                *reinterpret_cast<float4*>(ws + tid * 4) = make_float4(0.f, 0.f, 0.f, 0.f);
        }

        float f[16];
        {
            const float* frow = feats + (size_t)(b * CC + cp) * SRC + p0 + pw;
#pragma unroll
            for (int q = 0; q < 4; ++q) {
                float4 t = *reinterpret_cast<const float4*>(frow + q * 4);
                f[q * 4 + 0] = t.x; f[q * 4 + 1] = t.y;
                f[q * 4 + 2] = t.z; f[q * 4 + 3] = t.w;
            }
        }
        __syncthreads();
        if constexpr (MODE != 2) gather_ws(L, ws, b, y, x0c, tid);
        __syncthreads();

        float acc[KC];
        if constexpr (MODE == 3) {
#pragma unroll
            for (int k = 0; k < KC; ++k) acc[k] = f[k & 15] * ws[k * PC];  // loop gutted
        } else {
#pragma unroll
            for (int k = 0; k < KC; ++k) {
                const float* wk = ws + k * PC + pw;
                float a0 = 0.f, a1 = 0.f, a2 = 0.f, a3 = 0.f;
#pragma unroll
                for (int q = 0; q < 4; ++q) {
                    float4 w4 = *reinterpret_cast<const float4*>(wk + q * 4);
                    a0 += w4.x * f[q * 4 + 0];
                    a1 += w4.y * f[q * 4 + 1];
                    a2 += w4.z * f[q * 4 + 2];
                    a3 += w4.w * f[q * 4 + 3];
                }
                acc[k] = (a0 + a1) + (a2 + a3);
            }
        }

        if constexpr (MODE == 1) {
            float sum = 0.f;
#pragma unroll
            for (int k = 0; k < KC; ++k) sum += acc[k];      // keep all acc live
            scratch[((size_t)(b * NS + s)) * 512 + tid] = sum;  // 2MB total
        } else {
            if (psub == 1) {
#pragma unroll
                for (int k = 0; k < KC; ++k) scr[k * CC + cp] = acc[k];
            }
            __syncthreads();
            if (psub == 0) {
                float* op = scratch + ((size_t)(b * NS + s)) * KC * CC + cp;
#pragma unroll
                for (int k = 0; k < KC; ++k)
                    op[(size_t)k * CC] = acc[k] + scr[k * CC + cp];
            }
        }
        __syncthreads();
        asm volatile("" ::: "memory");
    }
}

// ---- k3: EXACT R16 version ---------------------------------------------------
__global__ __launch_bounds__(256)
void k3_finalize(const float* __restrict__ partial,
                 const float* __restrict__ partialw,
                 float* __restrict__ out)
{
    int k = blockIdx.x, b = blockIdx.y;
    int tid = threadIdx.x;

    const float* base = partial + ((size_t)(b * NS) * KC + k) * CC + tid;
    float acc = 0.f;
#pragma unroll 8
    for (int s = 0; s < NS; ++s) acc += base[(size_t)s * KC * CC];

    __shared__ float red[2];
    float v = 0.f;
    if (tid < NS) v = partialw[(size_t)(b * NS + tid) * KC + k];
#pragma unroll
    for (int off = 32; off; off >>= 1) v += __shfl_down(v, off);
    if (tid < NS && (tid & 63) == 0) red[tid >> 6] = v;
    __syncthreads();
    float cnt = red[0] + red[1];

    atomicAdd(&out[k * CC + tid], acc / (8.f * (cnt + 1e-6f)));
}

extern "C" void kernel_launch(void* const* d_in, const int* in_sizes, int n_in,
                              void* d_out, int out_size, void* d_ws, size_t ws_size,
                              hipStream_t stream) {
    const float* feats = (const float*)d_in[0];
    const float* preds = (const float*)d_in[1];
    const int*   masks = (const int*)  d_in[2];
    float* out = (float*)d_out;

    float* wsf = (float*)d_ws;
    unsigned char* L = (unsigned char*)d_ws;
    float* partialw = wsf + WSF_PARTW;
    float* partial  = wsf + WSF_PART;

    // real chain (R16, verified) — out depends only on these three
    k1_classify<<<(BB * HWP / 4) / 256, 256, 0, stream>>>(preds, masks, L, out);
    k2_contract<<<dim3(NS, BB), 512, 0, stream>>>(feats, L, partial, partialw);
    k3_finalize<<<dim3(KC, BB), 256, 0, stream>>>(partial, partialw, out);

    // ablation probes -> dead scratch slices at 128/160/192/224 MB
    char* base = (char*)d_ws;
    float* s0 = (float*)(base + (size_t)128 * 1024 * 1024);
    float* s1 = (float*)(base + (size_t)160 * 1024 * 1024);
    float* s2 = (float*)(base + (size_t)192 * 1024 * 1024);
    float* s3 = (float*)(base + (size_t)224 * 1024 * 1024);
    k2_probe<0><<<dim3(NS, BB), 512, 0, stream>>>(feats, L, s0);  // full clone x2
    k2_probe<1><<<dim3(NS, BB), 512, 0, stream>>>(feats, L, s1);  // no stores  x3
    k2_probe<2><<<dim3(NS, BB), 512, 0, stream>>>(feats, L, s2);  // no gather  x3
    k2_probe<3><<<dim3(NS, BB), 512, 0, stream>>>(feats, L, s3);  // no fma     x3
}

// Round 18
// 44.609 us; speedup vs baseline: 15.4878x; 15.4878x over previous
//
#include <hip/hip_runtime.h>

#define KC   21      // num classes
#define BB   8       // batch
#define CC   256     // feat channels
#define HWP  65536   // 256*256 output pixels per image
#define SRC  4096    // 64*64 source pixels
#define NS   128     // p-chunks of 32
#define PC   32      // p per chunk

// d_ws layout: L bytes [0, 524288) | counts f32 @ byte 524288 (256 floats) |
// partial f32 @ float idx 131328 (22 MB) | Wg f32 @ byte 32MB (2.75 MB). Disjoint.
#define WSF_COUNTS 131072
#define WSF_PART   (WSF_COUNTS + 256)
#define WSF_WG     8388608                    // float idx (byte 32 MB)

// ---- k1: per-pixel argmax + gt-match -> label map (proven body) -------------
__global__ __launch_bounds__(256, 2)
void k1_classify(const float* __restrict__ preds,
                 const int*   __restrict__ masks,
                 unsigned char* __restrict__ L,
                 float* __restrict__ out,
                 float* __restrict__ counts)
{
    int tid = threadIdx.x;
    if (blockIdx.x == 0) {
        float4* o4 = reinterpret_cast<float4*>(out);
#pragma unroll
        for (int i = 0; i < (KC * CC / 4 + 255) / 256; ++i) {
            int j = tid + i * 256;
            if (j < KC * CC / 4) o4[j] = make_float4(0.f, 0.f, 0.f, 0.f);
        }
        if (tid < 64)   // zero counts (256 floats)
            reinterpret_cast<float4*>(counts)[tid] = make_float4(0.f, 0.f, 0.f, 0.f);
    }

    int idx = blockIdx.x * 256 + tid;
    int b   = idx >> 14;
    int hw4 = (idx & 16383) << 2;

    const float* pb = preds + (size_t)b * KC * HWP + hw4;
    float va[4][KC];
#pragma unroll
    for (int k = 0; k < KC; ++k) {
        float4 t = *reinterpret_cast<const float4*>(pb + (size_t)k * HWP);
        va[0][k] = t.x; va[1][k] = t.y; va[2][k] = t.z; va[3][k] = t.w;
    }
    int4 mm = *reinterpret_cast<const int4*>(masks + b * HWP + hw4);
    int mk[4] = { mm.x, mm.y, mm.z, mm.w };

    uchar4 r;
    unsigned char* rp = reinterpret_cast<unsigned char*>(&r);
#pragma unroll
    for (int j = 0; j < 4; ++j) {
        float best = va[j][0];
        int   bi   = 0;
#pragma unroll
        for (int k = 1; k < KC; ++k)
            if (va[j][k] > best) { best = va[j][k]; bi = k; }
        rp[j] = (mk[j] == bi) ? (unsigned char)bi : (unsigned char)255;
    }
    *reinterpret_cast<uchar4*>(L + (size_t)b * HWP + hw4) = r;
}

// ---- kW: build W[b][k][4096] in GLOBAL + exact counts ------------------------
// Block (y, b): full source row y (64 cells). Gather over hi-res rows
// [4y-2, 4y+5] x all 256 cols into LDS (dyadic-exact atomics), write out
// coalesced. counts via global atomicAdd of exact dyadic rowsums (all partial
// sums are n/64 with n <= 2^22 -> exactly representable -> order-independent).
__global__ __launch_bounds__(256)
void kW_build(const unsigned char* __restrict__ L,
              float* __restrict__ Wg,          // [B][K][SRC]
              float* __restrict__ counts)      // [B][K]
{
    __shared__ float ws[KC * 64];              // 5.25 KB
    int y = blockIdx.x, b = blockIdx.y;
    int tid = threadIdx.x;

    for (int t = tid; t < KC * 16; t += 256)   // zero 336 float4
        *reinterpret_cast<float4*>(ws + t * 4) = make_float4(0.f, 0.f, 0.f, 0.f);
    __syncthreads();

    {
        int r = tid >> 5, cb = tid & 31;       // 8 rows x 32 threads
        int h = 4 * y - 2 + r;
        if ((unsigned)h < 256u) {
            float sy = h * 0.25f - 0.375f;
            int   yt = (int)floorf(sy);
            float wy = sy - (float)yt;
            int ya = yt < 0 ? 0 : yt;
            int yb = yt + 1 > 63 ? 63 : yt + 1;
            float wyy = ((ya == y) ? (1.f - wy) : 0.f) + ((yb == y) ? wy : 0.f);
            if (wyy != 0.f) {
                const unsigned char* Lrow = L + ((size_t)b << 16) + ((size_t)h << 8);
#pragma unroll
                for (int j = 0; j < 8; ++j) {
                    int w = cb + j * 32;       // all 256 cols
                    int k = Lrow[w];
                    if (k < KC) {
                        float sx = w * 0.25f - 0.375f;
                        int   xt = (int)floorf(sx);
                        float wx = sx - (float)xt;
                        int xa = xt < 0 ? 0 : xt;
                        int xb = xt + 1 > 63 ? 63 : xt + 1;
                        atomicAdd(&ws[k * 64 + xa], wyy * (1.f - wx));  // dyadic-exact
                        atomicAdd(&ws[k * 64 + xb], wyy * wx);
                    }
                }
            }
        }
    }
    __syncthreads();

    // counts: exact dyadic rowsums, one global atomic per (k)
    if (tid < KC) {
        float sw = 0.f;
#pragma unroll
        for (int x = 0; x < 64; ++x) sw += ws[tid * 64 + ((x + tid) & 63)];
        if (sw != 0.f) atomicAdd(&counts[b * KC + tid], sw);
    }

    // write W row: 336 float4, coalesced per k
    for (int t = tid; t < KC * 16; t += 256) {
        int k = t >> 4, q = t & 15;
        *reinterpret_cast<float4*>(Wg + (size_t)(b * KC + k) * SRC + y * 64 + q * 4) =
            *reinterpret_cast<const float4*>(ws + k * 64 + q * 4);
    }
}

// ---- k2: ZERO-LDS contraction; W via SCALAR loads (block-uniform address) ----
// Thread = channel. f[32] in VGPRs; W addresses depend only on blockIdx/loop
// constants -> provably wave-uniform -> s_load through the scalar cache; FMA
// takes W from SGPRs. No LDS, no barriers, no atomics.
__global__ __launch_bounds__(256, 4)
void k2_contract(const float* __restrict__ feats,   // [B][C][SRC]
                 const float* __restrict__ Wg,      // [B][K][SRC]
                 float* __restrict__ partial)       // [B][NS][K][C]
{
    int s = blockIdx.x, b = blockIdx.y;
    int c = threadIdx.x;
    int p0 = s * PC;

    float f[PC];
    {
        const float* frow = feats + (size_t)(b * CC + c) * SRC + p0;
#pragma unroll
        for (int q = 0; q < PC / 4; ++q) {
            float4 t = *reinterpret_cast<const float4*>(frow + q * 4);
            f[q * 4 + 0] = t.x; f[q * 4 + 1] = t.y;
            f[q * 4 + 2] = t.z; f[q * 4 + 3] = t.w;
        }
    }

    const float* wb = Wg + (size_t)b * KC * SRC + p0;
    float* op = partial + ((size_t)(b * NS + s)) * KC * CC + c;

#pragma unroll 3
    for (int k = 0; k < KC; ++k) {
        const float* wk = wb + (size_t)k * SRC;    // uniform -> scalar pipe
        float a0 = 0.f, a1 = 0.f, a2 = 0.f, a3 = 0.f;
#pragma unroll
        for (int q = 0; q < PC / 4; ++q) {
            float w0 = wk[q * 4 + 0], w1 = wk[q * 4 + 1];
            float w2 = wk[q * 4 + 2], w3 = wk[q * 4 + 3];
            a0 += w0 * f[q * 4 + 0];
            a1 += w1 * f[q * 4 + 1];
            a2 += w2 * f[q * 4 + 2];
            a3 += w3 * f[q * 4 + 3];
        }
        op[(size_t)k * CC] = (a0 + a1) + (a2 + a3);   // coalesced store
    }
}

// ---- k3: reduce chunks, normalize by counts, batch-mean ----------------------
__global__ __launch_bounds__(256)
void k3_finalize(const float* __restrict__ partial,   // [B][NS][K][C]
                 const float* __restrict__ counts,    // [B][K]
                 float* __restrict__ out)             // [K][C], zeroed by k1
{
    int k = blockIdx.x, b = blockIdx.y;
    int tid = threadIdx.x;

    const float* base = partial + ((size_t)(b * NS) * KC + k) * CC + tid;
    float acc = 0.f;
#pragma unroll 8
    for (int s = 0; s < NS; ++s) acc += base[(size_t)s * KC * CC];

    float cnt = counts[b * KC + k];    // exact integer-valued
    atomicAdd(&out[k * CC + tid], acc / (8.f * (cnt + 1e-6f)));
}

extern "C" void kernel_launch(void* const* d_in, const int* in_sizes, int n_in,
                              void* d_out, int out_size, void* d_ws, size_t ws_size,
                              hipStream_t stream) {
    const float* feats = (const float*)d_in[0];   // [8,256,64,64]
    const float* preds = (const float*)d_in[1];   // [8,21,256,256]
    const int*   masks = (const int*)  d_in[2];   // [8,256,256]
    float* out = (float*)d_out;                   // [21,256]

    float* wsf = (float*)d_ws;
    unsigned char* L = (unsigned char*)d_ws;      // 512 KB, fully written by k1
    float* counts  = wsf + WSF_COUNTS;
    float* partial = wsf + WSF_PART;
    float* Wg      = wsf + WSF_WG;

    k1_classify<<<(BB * HWP / 4) / 256, 256, 0, stream>>>(preds, masks, L, out, counts);
    kW_build<<<dim3(64, BB), 256, 0, stream>>>(L, Wg, counts);
    k2_contract<<<dim3(NS, BB), 256, 0, stream>>>(feats, Wg, partial);
    k3_finalize<<<dim3(KC, BB), 256, 0, stream>>>(partial, counts, out);
}